// Round 9
// baseline (115.253 us; speedup 1.0000x reference)
//
#include <hip/hip_runtime.h>

typedef float v2f __attribute__((ext_vector_type(2)));
typedef float v4f __attribute__((ext_vector_type(4)));

#define HW      1024   // H*W = BN channel count (spatial positions)
#define NROWS   4096   // B*C = reduction size per channel
#define NLAYERS 30
#define TPB     256

// ---------------------------------------------------------------------------
// Packed-f32 VOP3P ops.
// ---------------------------------------------------------------------------
static __device__ __forceinline__ v2f pk_fma(v2f a, v2f b, v2f c) {
    v2f d; asm("v_pk_fma_f32 %0, %1, %2, %3" : "=v"(d) : "v"(a), "v"(b), "v"(c));
    return d;
}
static __device__ __forceinline__ v2f pk_add(v2f a, v2f b) {
    v2f d; asm("v_pk_add_f32 %0, %1, %2" : "=v"(d) : "v"(a), "v"(b));
    return d;
}
static __device__ __forceinline__ v2f pk_mul(v2f a, v2f b) {
    v2f d; asm("v_pk_mul_f32 %0, %1, %2" : "=v"(d) : "v"(a), "v"(b));
    return d;
}

// ---------------------------------------------------------------------------
// DPP-based wave64 sum: pure VALU, lane 63 = wave total.
// ---------------------------------------------------------------------------
template <int CTRL, int RMASK>
__device__ __forceinline__ float dpp_add(float x) {
    int t = __builtin_amdgcn_update_dpp(0, __builtin_bit_cast(int, x),
                                        CTRL, RMASK, 0xf, true);
    return x + __builtin_bit_cast(float, t);
}
__device__ __forceinline__ float wave_sum64(float x) {
    x = dpp_add<0x111, 0xf>(x);   // row_shr:1
    x = dpp_add<0x112, 0xf>(x);   // row_shr:2
    x = dpp_add<0x114, 0xf>(x);   // row_shr:4
    x = dpp_add<0x118, 0xf>(x);   // row_shr:8
    x = dpp_add<0x142, 0xa>(x);   // row_bcast15 -> rows 1,3
    x = dpp_add<0x143, 0xc>(x);   // row_bcast31 -> rows 2,3
    return x;                     // lane 63 = wave total
}

// ---------------------------------------------------------------------------
// Generic 64x64-tile transpose (verified R7/R8): dst[n*M+m] = src[m*N+n].
// ---------------------------------------------------------------------------
__global__ __launch_bounds__(TPB) void txp64(const float* __restrict__ src,
                                             float* __restrict__ dst,
                                             int M, int N) {
    __shared__ float tile[64][65];
    const int n0 = blockIdx.x * 64;
    const int m0 = blockIdx.y * 64;
    const int tx = threadIdx.x & 63;
    const int ty = threadIdx.x >> 6;    // 0..3
#pragma unroll
    for (int i = 0; i < 16; ++i) {
        const int r = ty + 4 * i;
        tile[r][tx] = src[(size_t)(m0 + r) * N + n0 + tx];
    }
    __syncthreads();
#pragma unroll
    for (int i = 0; i < 16; ++i) {
        const int r = ty + 4 * i;
        dst[(size_t)(n0 + r) * M + m0 + tx] = tile[tx][r];
    }
}

// ---------------------------------------------------------------------------
// Main kernel, register-feasible point: TWO waves per channel row (128 thr),
// 32 elems/lane -> x1/y/z = 16 v2f each (~130 VGPR total, no spill/remat —
// the R2/R8 1-wave design needed ~230 and the compiler quietly spilled).
// Grid 1024 x 2 waves = 2 waves/SIMD: the co-resident wave hides the other's
// DPP/stats serial chain. Cross-wave combine: DPP -> 2 v2f partials in LDS
// -> one barrier -> v4f read + 2 adds. Lane t owns e = 4t + 512j + i
// (j=0..7, i=0..3): coalesced dwordx4, c = (4t+i)&255 constant in j.
// ---------------------------------------------------------------------------
__global__ __launch_bounds__(128, 2) void ode_row2w(
    float* ws, const float* __restrict__ delta_t,
    const float* __restrict__ matrices, const float* __restrict__ gamma,
    const float* __restrict__ beta) {

    const int p    = blockIdx.x;
    const int t    = threadIdx.x;        // 0..127
    const int wid  = t >> 6;             // 0/1
    const int lane = t & 63;
    const int c0   = (4 * t) & 255;      // matrix quad base
    float* row = ws + (size_t)p * NROWS;

    __shared__ __align__(16) v2f red[2][2];   // [parity][wave] = (s,q)

    // Coalesced gather: 8x dwordx4 (1 KB per wave-instruction).
    v2f x1[16], y[16], z[16];
#pragma unroll
    for (int j = 0; j < 8; ++j) {
        const v4f q4 = *(const v4f*)(row + 4 * t + 512 * j);
        x1[2 * j]     = (v2f){q4.x, q4.y};
        x1[2 * j + 1] = (v2f){q4.z, q4.w};
        y[2 * j]     = x1[2 * j];
        y[2 * j + 1] = x1[2 * j + 1];
    }

    const float gp = gamma[p];
    const float bp = beta[p];

    // Layer 0: z0 = m0*x1 + x1 (y0 = x1); reduce; post partials to red[0].
    {
        const v4f m4 = *(const v4f*)(matrices + c0);
        const v2f mA = {m4.x, m4.y}, mB = {m4.z, m4.w};
        v2f s0 = {0.f, 0.f}, s1 = {0.f, 0.f}, q0 = {0.f, 0.f}, q1 = {0.f, 0.f};
#pragma unroll
        for (int j = 0; j < 8; ++j) {
            z[2 * j]     = pk_fma(mA, x1[2 * j], y[2 * j]);
            z[2 * j + 1] = pk_fma(mB, x1[2 * j + 1], y[2 * j + 1]);
            s0 = pk_add(s0, z[2 * j]);
            q0 = pk_fma(z[2 * j], z[2 * j], q0);
            s1 = pk_add(s1, z[2 * j + 1]);
            q1 = pk_fma(z[2 * j + 1], z[2 * j + 1], q1);
        }
        const v2f sv = pk_add(s0, s1);
        const v2f qv = pk_add(q0, q1);
        const float ss = wave_sum64(sv.x + sv.y);
        const float qq = wave_sum64(qv.x + qv.y);
        if (lane == 63) red[0][wid] = (v2f){ss, qq};
    }

    v4f   mq  = *(const v4f*)(matrices + 256 + c0);   // m_1 quad
    float dtc = delta_t[0];
    float dtn = delta_t[1];
    __syncthreads();

    for (int k = 0; k < NLAYERS - 1; ++k) {
        // Prefetch m_{k+2}/dt_{k+2}; lands under stats + pass.
        const int k2 = (k + 2 < NLAYERS) ? k + 2 : NLAYERS - 1;
        const v4f   mq_n  = *(const v4f*)(matrices + k2 * 256 + c0);
        const float dt_nn = delta_t[k2];

        // Combine 2 wave-partials: one v4f LDS read + 2 adds.
        const int par = k & 1;
        const v4f r = *(const v4f*)&red[par][0];   // s0,q0,s1,q1
        const float S = r.x + r.z;
        const float Q = r.y + r.w;

        const float dtk  = __builtin_amdgcn_fmed3f(dtc, 0.0f, 6.0f);
        const float mean = S * (1.0f / 4096.0f);
        const float var  = fmaf(-mean, mean, Q * (1.0f / 4096.0f));
        const float rstd = rsqrtf(var + 1e-5f);
        const float g    = gp * rstd;            // fold gamma into scale
        const float b    = fmaf(-mean, g, bp);   // fold mean into bias
        const v2f g2 = {g, g}, b2 = {b, b};
        const v2f dt2 = {dtk, dtk};
        const v2f om2 = {1.0f - dtk, 1.0f - dtk};
        const v2f mA = {mq.x, mq.y}, mB = {mq.z, mq.w};

        // Fused pass: apply layer k, build z_{k+1} and its s/q partials.
        v2f s0 = {0.f, 0.f}, s1 = {0.f, 0.f}, q0 = {0.f, 0.f}, q1 = {0.f, 0.f};
#pragma unroll
        for (int j = 0; j < 8; ++j) {
#pragma unroll
            for (int h = 0; h < 2; ++h) {
                const int e = 2 * j + h;
                v2f a = pk_fma(z[e], g2, b2);
                a.x = __builtin_amdgcn_fmed3f(a.x, 0.0f, 6.0f);
                a.y = __builtin_amdgcn_fmed3f(a.y, 0.0f, 6.0f);
                v2f yy = pk_mul(om2, y[e]);          // y *= (1-dt)
                y[e] = pk_fma(dt2, a, yy);           // y += dt*a
                z[e] = pk_fma(h ? mB : mA, x1[e], y[e]);
                if (h == 0) { s0 = pk_add(s0, z[e]); q0 = pk_fma(z[e], z[e], q0); }
                else        { s1 = pk_add(s1, z[e]); q1 = pk_fma(z[e], z[e], q1); }
            }
        }
        const v2f sv = pk_add(s0, s1);
        const v2f qv = pk_add(q0, q1);
        const float ss = wave_sum64(sv.x + sv.y);
        const float qq = wave_sum64(qv.x + qv.y);
        if (lane == 63) red[par ^ 1][wid] = (v2f){ss, qq};

        mq = mq_n; dtc = dtn; dtn = dt_nn;
        __syncthreads();
    }

    // Final layer (k = 29): combine red[1], apply, out = y + x1 into ws row.
    {
        const v4f r = *(const v4f*)&red[(NLAYERS - 1) & 1][0];
        const float S = r.x + r.z;
        const float Q = r.y + r.w;

        const float dtk  = __builtin_amdgcn_fmed3f(dtc, 0.0f, 6.0f);
        const float mean = S * (1.0f / 4096.0f);
        const float var  = fmaf(-mean, mean, Q * (1.0f / 4096.0f));
        const float rstd = rsqrtf(var + 1e-5f);
        const float g    = gp * rstd;
        const float b    = fmaf(-mean, g, bp);
        const v2f g2 = {g, g}, b2 = {b, b};
        const v2f dt2 = {dtk, dtk};
        const v2f om2 = {1.0f - dtk, 1.0f - dtk};

#pragma unroll
        for (int j = 0; j < 8; ++j) {
            v2f o0, o1;
#pragma unroll
            for (int h = 0; h < 2; ++h) {
                const int e = 2 * j + h;
                v2f a = pk_fma(z[e], g2, b2);
                a.x = __builtin_amdgcn_fmed3f(a.x, 0.0f, 6.0f);
                a.y = __builtin_amdgcn_fmed3f(a.y, 0.0f, 6.0f);
                v2f yy = pk_mul(om2, y[e]);
                yy = pk_fma(dt2, a, yy);
                const v2f o = pk_add(yy, x1[e]);
                if (h == 0) o0 = o; else o1 = o;
            }
            v4f o4; o4.x = o0.x; o4.y = o0.y; o4.z = o1.x; o4.w = o1.y;
            *(v4f*)(row + 4 * t + 512 * j) = o4;
        }
    }
}

// ---------------------------------------------------------------------------
// Fallback (proven 55.6 us, round 0): used only if workspace is too small.
// ---------------------------------------------------------------------------
__global__ __launch_bounds__(TPB) void ode_fused(const float* __restrict__ x,
                                                 const float* __restrict__ delta_t,
                                                 const float* __restrict__ matrices,
                                                 const float* __restrict__ gamma,
                                                 const float* __restrict__ beta,
                                                 float* __restrict__ out) {
    const int bid = blockIdx.x;
    const int p   = ((bid & 7) << 7) | (bid >> 3);
    const int t   = threadIdx.x;

    __shared__ float smat[(NLAYERS + 1) * 256];
    __shared__ float sdt[NLAYERS];
    __shared__ __align__(16) v2f red[2][4];

#pragma unroll
    for (int i = 0; i < NLAYERS; ++i)
        smat[i * 256 + t] = matrices[i * 256 + t];
    if (t < NLAYERS)
        sdt[t] = __builtin_amdgcn_fmed3f(delta_t[t], 0.0f, 6.0f);

    v2f x1[8], y[8];
#pragma unroll
    for (int k = 0; k < 8; ++k) {
        x1[k].x = x[(size_t)(t + 512 * k) * HW + p];
        x1[k].y = x[(size_t)(t + 512 * k + 256) * HW + p];
        y[k] = x1[k];
    }

    const float gp   = gamma[p];
    const float bp   = beta[p];
    const int   wid  = t >> 6;
    const int   lane = t & 63;

    __syncthreads();
    float m_cur = smat[t];

    for (int l = 0; l < NLAYERS; ++l) {
        const float dtl = sdt[l];
        const v2f m2    = {m_cur, m_cur};
        const v2f dt2   = {dtl, dtl};
        const v2f om2   = {1.0f - dtl, 1.0f - dtl};

        v2f z[8];
        v2f sA = {0.f, 0.f}, sB = {0.f, 0.f};
        v2f qA = {0.f, 0.f}, qB = {0.f, 0.f};
#pragma unroll
        for (int k = 0; k < 8; k += 2) {
            z[k]     = __builtin_elementwise_fma(m2, x1[k], y[k]);
            z[k + 1] = __builtin_elementwise_fma(m2, x1[k + 1], y[k + 1]);
            sA += z[k];
            sB += z[k + 1];
            qA = __builtin_elementwise_fma(z[k], z[k], qA);
            qB = __builtin_elementwise_fma(z[k + 1], z[k + 1], qB);
        }
#pragma unroll
        for (int k = 0; k < 8; ++k) y[k] *= om2;

        const v2f sv = sA + sB;
        const v2f qv = qA + qB;
        float s = wave_sum64(sv.x + sv.y);
        float q = wave_sum64(qv.x + qv.y);

        const int par = l & 1;
        if (lane == 63) { v2f w; w.x = s; w.y = q; red[par][wid] = w; }
        m_cur = smat[(l + 1) * 256 + t];
        __syncthreads();

        const float4 r0 = *(const float4*)&red[par][0];
        const float4 r1 = *(const float4*)&red[par][2];
        const float S  = (r0.x + r0.z) + (r1.x + r1.z);
        const float S2 = (r0.y + r0.w) + (r1.y + r1.w);

        const float mean = S * (1.0f / 4096.0f);
        const float var  = fmaf(-mean, mean, S2 * (1.0f / 4096.0f));
        const float rstd = rsqrtf(var + 1e-5f);
        const float g    = gp * rstd;
        const float bb   = fmaf(-mean, g, bp);
        const v2f g2 = {g, g}, b2 = {bb, bb};
        const v2f z0 = {0.f, 0.f}, s6 = {6.f, 6.f};
#pragma unroll
        for (int k = 0; k < 8; ++k) {
            v2f a = __builtin_elementwise_fma(z[k], g2, b2);
            a = __builtin_elementwise_max(a, z0);
            a = __builtin_elementwise_min(a, s6);
            y[k] = __builtin_elementwise_fma(dt2, a, y[k]);
        }
    }

#pragma unroll
    for (int k = 0; k < 8; ++k) {
        out[(size_t)(t + 512 * k) * HW + p]       = y[k].x + x1[k].x;
        out[(size_t)(t + 512 * k + 256) * HW + p] = y[k].y + x1[k].y;
    }
}

extern "C" void kernel_launch(void* const* d_in, const int* in_sizes, int n_in,
                              void* d_out, int out_size, void* d_ws, size_t ws_size,
                              hipStream_t stream) {
    const float* x        = (const float*)d_in[0];   // [16,256,32,32]
    const float* delta_t  = (const float*)d_in[1];   // [30,1]
    const float* matrices = (const float*)d_in[2];   // [30,1,1,16,16]
    const float* gamma    = (const float*)d_in[3];   // [1024]
    const float* beta     = (const float*)d_in[4];   // [1024]
    float* out = (float*)d_out;

    const size_t need = (size_t)HW * NROWS * sizeof(float);   // 16 MiB
    if (d_ws != nullptr && ws_size >= need) {
        float* ws = (float*)d_ws;
        // T1: x [4096,1024] -> ws = x^T [1024,4096]
        txp64<<<dim3(HW / 64, NROWS / 64), dim3(TPB), 0, stream>>>(x, ws, NROWS, HW);
        // Main: 2 waves per channel row, register-feasible, in place.
        ode_row2w<<<dim3(HW), dim3(128), 0, stream>>>(ws, delta_t, matrices, gamma, beta);
        // T2: ws [1024,4096] -> out [4096,1024]
        txp64<<<dim3(NROWS / 64, HW / 64), dim3(TPB), 0, stream>>>(ws, out, HW, NROWS);
    } else {
        ode_fused<<<dim3(HW), dim3(TPB), 0, stream>>>(x, delta_t, matrices, gamma, beta, out);
    }
}